// Round 6
// baseline (39.850 us; speedup 1.0000x reference)
//
#include <hip/hip_runtime.h>
#include <math.h>

#define NQ 8
#define DEPTH 3
#define FDIM 16
#define HDIM 256
#define WAVES_PER_BLOCK 4
#define THREADS (WAVES_PER_BLOCK * 64)
#define ROWS_PER_BLOCK (WAVES_PER_BLOCK * 2)
#define NGATE (NQ * DEPTH)        // 24 (RZ,RY) pairs

// ---------------- cross-lane xor shuffles ----------------
template<int CTRL>
__device__ __forceinline__ float dpp1(float v) {
    return __int_as_float(__builtin_amdgcn_update_dpp(
        0, __float_as_int(v), CTRL, 0xF, 0xF, true));
}

// single-DPP xor masks used by wred (VALU, lowest latency)
template<int M4>
__device__ __forceinline__ float shuf4(float v) {
    if constexpr (M4 == 1)  return dpp1<0xB1>(v);   // quad_perm xor1
    else if constexpr (M4 == 2)  return dpp1<0x4E>(v);   // quad_perm xor2
    else if constexpr (M4 == 4)  return dpp1<0x1B>(dpp1<0x141>(v)); // xor3 o xor7
    else if constexpr (M4 == 8)  return dpp1<0x128>(v);  // row_ror:8 == xor8
    else return v;
}

// general 6-bit xor shuffle on the LDS pipe (0 VALU slots):
// ds_swizzle BitMode for masks 1..31, ds_bpermute for masks with bit5 set.
template<int ML>
__device__ __forceinline__ float shuf(float v, int lane) {
    if constexpr (ML == 0) {
        return v;
    } else if constexpr (ML >= 32) {
        int addr = (lane ^ ML) << 2;   // CSE'd across the 16 uses per gate
        return __int_as_float(__builtin_amdgcn_ds_bpermute(addr, __float_as_int(v)));
    } else {
        return __int_as_float(__builtin_amdgcn_ds_swizzle(
            __float_as_int(v), (ML << 10) | 0x1F));   // xor=ML, and=0x1F
    }
}

// full 64-lane sum, all lanes receive the total.
// permlane*_swap trick: r[0]+r[1] == v + v[lane^K] for every lane (no select).
__device__ __forceinline__ float wred(float v, int lane) {
    v += shuf4<1>(v);
    v += shuf4<2>(v);
    v += shuf4<4>(v);
    v += shuf4<8>(v);
#if __has_builtin(__builtin_amdgcn_permlane16_swap)
    {
        auto r = __builtin_amdgcn_permlane16_swap(__float_as_int(v), __float_as_int(v), false, false);
        v = __int_as_float(r[0]) + __int_as_float(r[1]);
    }
#else
    v += __shfl_xor(v, 16, 64);
#endif
#if __has_builtin(__builtin_amdgcn_permlane32_swap)
    {
        auto r = __builtin_amdgcn_permlane32_swap(__float_as_int(v), __float_as_int(v), false, false);
        v = __int_as_float(r[0]) + __int_as_float(r[1]);
    }
#else
    v += __shfl_xor(v, 32, 64);
#endif
    return v;
}

__device__ __forceinline__ float fast_tanh(float y) {
    float ex = __expf(2.f * y);                       // inf for large y -> t=1
    return 1.f - 2.f * __builtin_amdgcn_rcpf(ex + 1.f);
}

// ---------------- relabeled gate, two rows per wave ----------------
// Physical storage never permuted. Layer-l gates use pair-mask M = A^l*e_b and
// parity row R = row_b(A^{-l}), both 8-bit compile-time constants over
// x = (hi<<6)|lane.  RZ: amp *= (cz + i*sgz).  RY: amp = cy*amp + sgy*partner.
// Signs sgz/sgy are lane-dependent but ROW-independent -> shared for both rows.
template<int M, int R>
__device__ __forceinline__ void gate2x2(float (&srA)[4], float (&siA)[4],
                                        float (&srB)[4], float (&siB)[4],
                                        float cz, float szv, float cy, float sy,
                                        int lane) {
    constexpr int ML = M & 63, MH = (M >> 6) & 3;
    constexpr int RL = R & 63, RH = (R >> 6) & 3;
    bool p0;
    if constexpr (RL == 0)                 p0 = false;
    else if constexpr ((RL & (RL-1)) == 0) p0 = (lane & RL) != 0;
    else                                   p0 = (__popc(lane & RL) & 1) != 0;
    float sgz = p0 ? szv : -szv;
    float sgy = p0 ? sy  : -sy;
    // RZ (diagonal phase), both rows
#pragma unroll
    for (int hi = 0; hi < 4; hi++) {
        const bool f = (__builtin_popcount(hi & RH) & 1) != 0;   // folds per-hi
        float z = f ? -sgz : sgz;
        float nrA = fmaf(srA[hi], cz, -(siA[hi] * z));
        float niA = fmaf(siA[hi], cz,  (srA[hi] * z));
        srA[hi] = nrA; siA[hi] = niA;
        float nrB = fmaf(srB[hi], cz, -(siB[hi] * z));
        float niB = fmaf(siB[hi], cz,  (srB[hi] * z));
        srB[hi] = nrB; siB[hi] = niB;
    }
    // RY partners from post-RZ values (16 DS ops, two independent chains)
    float prA[4], piA[4], prB[4], piB[4];
#pragma unroll
    for (int hi = 0; hi < 4; hi++) {
        prA[hi] = shuf<ML>(srA[hi ^ MH], lane);
        piA[hi] = shuf<ML>(siA[hi ^ MH], lane);
        prB[hi] = shuf<ML>(srB[hi ^ MH], lane);
        piB[hi] = shuf<ML>(siB[hi ^ MH], lane);
    }
#pragma unroll
    for (int hi = 0; hi < 4; hi++) {
        const bool f = (__builtin_popcount(hi & RH) & 1) != 0;
        float yv = f ? -sgy : sgy;
        srA[hi] = fmaf(yv, prA[hi], cy * srA[hi]);
        siA[hi] = fmaf(yv, piA[hi], cy * siA[hi]);
        srB[hi] = fmaf(yv, prB[hi], cy * srB[hi]);
        siB[hi] = fmaf(yv, piB[hi], cy * siB[hi]);
    }
}

__global__ __launch_bounds__(THREADS, 8) void hqcl_kernel(
    const float* __restrict__ x,     // (B,16)
    const float* __restrict__ w1,    // (256,16)
    const float* __restrict__ b1,    // (256)
    const float* __restrict__ w2,    // (8,256)
    const float* __restrict__ b2,    // (8)
    const float* __restrict__ qp,    // (48)
    const float* __restrict__ dw1,   // (256,1)
    const float* __restrict__ db1,   // (256)
    const float* __restrict__ dw2,   // (1,256)
    const float* __restrict__ db2,   // (1)
    float* __restrict__ out, int B)
{
    __shared__ float4 sG4[NGATE];    // (cz,sz,cy,sy) per gate; gate g: qp[2g], qp[2g+1]

    const int t = threadIdx.x;
    if (t < 2 * NGATE) {
        float s, c;
        __sincosf(qp[t] * 0.5f, &s, &c);
        float* p = (float*)&sG4[t >> 1] + 2 * (t & 1);
        p[0] = c; p[1] = s;
    }
    __syncthreads();

    const int lane = t & 63;
    const int row0 = blockIdx.x * ROWS_PER_BLOCK + (t >> 6) * 2;   // rows row0, row0+1
    if (row0 >= B) return;

    // ---- encoder: h = relu(x @ W1^T + b1), two rows ----
    const float4* xA = (const float4*)(x + row0 * FDIM);
    const float4* xB = (const float4*)(x + (row0 + 1) * FDIM);
    float4 xa0 = xA[0], xa1 = xA[1], xa2 = xA[2], xa3 = xA[3];
    float4 xb0 = xB[0], xb1 = xB[1], xb2 = xB[2], xb3 = xB[3];

    float hA[4], hB[4];
#pragma unroll
    for (int m = 0; m < 4; m++) {
        int j = lane + 64 * m;
        const float4* wp = (const float4*)(w1 + j * FDIM);
        float4 wa = wp[0], wb = wp[1], wc = wp[2], wd = wp[3];
        float bv = b1[j];
        float aA = bv, aB = bv;
        aA = fmaf(xa0.x, wa.x, aA); aA = fmaf(xa0.y, wa.y, aA);
        aA = fmaf(xa0.z, wa.z, aA); aA = fmaf(xa0.w, wa.w, aA);
        aA = fmaf(xa1.x, wb.x, aA); aA = fmaf(xa1.y, wb.y, aA);
        aA = fmaf(xa1.z, wb.z, aA); aA = fmaf(xa1.w, wb.w, aA);
        aA = fmaf(xa2.x, wc.x, aA); aA = fmaf(xa2.y, wc.y, aA);
        aA = fmaf(xa2.z, wc.z, aA); aA = fmaf(xa2.w, wc.w, aA);
        aA = fmaf(xa3.x, wd.x, aA); aA = fmaf(xa3.y, wd.y, aA);
        aA = fmaf(xa3.z, wd.z, aA); aA = fmaf(xa3.w, wd.w, aA);
        aB = fmaf(xb0.x, wa.x, aB); aB = fmaf(xb0.y, wa.y, aB);
        aB = fmaf(xb0.z, wa.z, aB); aB = fmaf(xb0.w, wa.w, aB);
        aB = fmaf(xb1.x, wb.x, aB); aB = fmaf(xb1.y, wb.y, aB);
        aB = fmaf(xb1.z, wb.z, aB); aB = fmaf(xb1.w, wb.w, aB);
        aB = fmaf(xb2.x, wc.x, aB); aB = fmaf(xb2.y, wc.y, aB);
        aB = fmaf(xb2.z, wc.z, aB); aB = fmaf(xb2.w, wc.w, aB);
        aB = fmaf(xb3.x, wd.x, aB); aB = fmaf(xb3.y, wd.y, aB);
        aB = fmaf(xb3.z, wd.z, aB); aB = fmaf(xb3.w, wd.w, aB);
        hA[m] = fmaxf(aA, 0.f);
        hB[m] = fmaxf(aB, 0.f);
    }

    // ---- angles = tanh(h @ W2^T + b2) * pi ----
    // angle/2 = tanh*pi/2 rad = tanh/4 revolutions -> native v_sin/v_cos range
    float c0A[NQ], s0A[NQ], c0B[NQ], s0B[NQ];
#pragma unroll
    for (int q = 0; q < NQ; q++) {
        float aA = 0.f, aB = 0.f;
#pragma unroll
        for (int m = 0; m < 4; m++) {
            float wv = w2[q * HDIM + lane + 64 * m];
            aA = fmaf(hA[m], wv, aA);
            aB = fmaf(hB[m], wv, aB);
        }
        aA = wred(aA, lane);
        aB = wred(aB, lane);
        float bq = b2[q];
        float uA = 0.25f * fast_tanh(aA + bq);
        float uB = 0.25f * fast_tanh(aB + bq);
        float svA, cvA, svB, cvB;
        asm("v_sin_f32 %0, %1" : "=v"(svA) : "v"(uA));
        asm("v_cos_f32 %0, %1" : "=v"(cvA) : "v"(uA));
        asm("v_sin_f32 %0, %1" : "=v"(svB) : "v"(uB));
        asm("v_cos_f32 %0, %1" : "=v"(cvB) : "v"(uB));
        s0A[q] = svA; c0A[q] = cvA;
        s0B[q] = svB; c0B[q] = cvB;
    }

    // ---- initial 8 RYs on |0..0> -> product state ----
    // amp index x = hi*64 + lane; qubit q <-> bit (7-q)
    float plA = 1.f, plB = 1.f;
#pragma unroll
    for (int b = 0; b < 6; b++) {
        int q = 7 - b;
        bool bit = (lane >> b) & 1;
        plA *= bit ? s0A[q] : c0A[q];
        plB *= bit ? s0B[q] : c0B[q];
    }
    float srA[4], siA[4], srB[4], siB[4];
    srA[0] = plA * c0A[1] * c0A[0];
    srA[1] = plA * s0A[1] * c0A[0];
    srA[2] = plA * c0A[1] * s0A[0];
    srA[3] = plA * s0A[1] * s0A[0];
    srB[0] = plB * c0B[1] * c0B[0];
    srB[1] = plB * s0B[1] * c0B[0];
    srB[2] = plB * c0B[1] * s0B[0];
    srB[3] = plB * s0B[1] * s0B[0];
#pragma unroll
    for (int hi = 0; hi < 4; hi++) { siA[hi] = 0.f; siB[hi] = 0.f; }

    // ---- circuit: CX chains folded into per-layer masks (GF(2) relabeling) ----
    // A cols: C1 03 06 0C 18 30 60 C0 ; A^2 cols: 61 C2 05 0A 14 28 50 A0
    // A^-1 rows: FF FE FC F8 F0 E0 C0 7F ; A^-2 rows: AA 55 AB 57 AF 5F BF D5
#define GATE(L, Q, MM, RR) { float4 g4 = sG4[(L)*8 + (Q)]; \
        gate2x2<MM, RR>(srA, siA, srB, siB, g4.x, g4.y, g4.z, g4.w, lane); }
    // layer 0 (identity labeling)
    GATE(0,0,0x80,0x80) GATE(0,1,0x40,0x40) GATE(0,2,0x20,0x20) GATE(0,3,0x10,0x10)
    GATE(0,4,0x08,0x08) GATE(0,5,0x04,0x04) GATE(0,6,0x02,0x02) GATE(0,7,0x01,0x01)
    // layer 1 (masks = cols of A, parities = rows of A^-1)
    GATE(1,0,0xC0,0x7F) GATE(1,1,0x60,0xC0) GATE(1,2,0x30,0xE0) GATE(1,3,0x18,0xF0)
    GATE(1,4,0x0C,0xF8) GATE(1,5,0x06,0xFC) GATE(1,6,0x03,0xFE) GATE(1,7,0xC1,0xFF)
    // layer 2 (masks = cols of A^2, parities = rows of A^-2)
    GATE(2,0,0xA0,0xD5) GATE(2,1,0x50,0xBF) GATE(2,2,0x28,0x5F) GATE(2,3,0x14,0xAF)
    GATE(2,4,0x0A,0x57) GATE(2,5,0x05,0xAB) GATE(2,6,0xC2,0x55) GATE(2,7,0x61,0xAA)
#undef GATE

    // ---- <Z_0> with final labeling: sign = parity(x & 0x4C) (row7 of A^-3) ----
    bool pb = (__popc(lane & 0x0C) & 1) != 0;
    float m0A = srA[0]*srA[0] + siA[0]*siA[0] + srA[2]*srA[2] + siA[2]*siA[2];
    float m1A = srA[1]*srA[1] + siA[1]*siA[1] + srA[3]*srA[3] + siA[3]*siA[3];
    float m0B = srB[0]*srB[0] + siB[0]*siB[0] + srB[2]*srB[2] + siB[2]*siB[2];
    float m1B = srB[1]*srB[1] + siB[1]*siB[1] + srB[3]*srB[3] + siB[3]*siB[3];
    float eA = pb ? (m1A - m0A) : (m0A - m1A);
    float eB = pb ? (m1B - m0B) : (m0B - m1B);
    eA = wred(eA, lane);
    eB = wred(eB, lane);

    // ---- decoder (weights shared across rows) ----
    float accA = 0.f, accB = 0.f;
#pragma unroll
    for (int m = 0; m < 4; m++) {
        int j = lane + 64 * m;
        float w1v = dw1[j], bv = db1[j], w2v = dw2[j];
        float dA = fmaxf(fmaf(eA, w1v, bv), 0.f);
        float dB = fmaxf(fmaf(eB, w1v, bv), 0.f);
        accA = fmaf(dA, w2v, accA);
        accB = fmaf(dB, w2v, accB);
    }
    accA = wred(accA, lane);
    accB = wred(accB, lane);
    if (lane == 0) {
        float bb = db2[0];
        out[row0] = 1.f / (1.f + __expf(-(accA + bb)));
        if (row0 + 1 < B)
            out[row0 + 1] = 1.f / (1.f + __expf(-(accB + bb)));
    }
}

extern "C" void kernel_launch(void* const* d_in, const int* in_sizes, int n_in,
                              void* d_out, int out_size, void* d_ws, size_t ws_size,
                              hipStream_t stream) {
    const float* x   = (const float*)d_in[0];
    const float* w1  = (const float*)d_in[1];
    const float* b1  = (const float*)d_in[2];
    const float* w2  = (const float*)d_in[3];
    const float* b2  = (const float*)d_in[4];
    const float* qp  = (const float*)d_in[5];
    const float* dw1 = (const float*)d_in[6];
    const float* db1 = (const float*)d_in[7];
    const float* dw2 = (const float*)d_in[8];
    const float* db2 = (const float*)d_in[9];
    float* out = (float*)d_out;

    const int B = in_sizes[0] / FDIM;
    const int grid = (B + ROWS_PER_BLOCK - 1) / ROWS_PER_BLOCK;
    hqcl_kernel<<<grid, THREADS, 0, stream>>>(x, w1, b1, w2, b2, qp, dw1, db1, dw2, db2, out, B);
}